// Round 1
// baseline (248.474 us; speedup 1.0000x reference)
//
#include <hip/hip_runtime.h>

// Problem constants (from reference setup_inputs):
//   x: (1, 3, 128, 128) fp32
//   w: (3, 124, 124, 25, 5, 5) fp32   (last two dims = (u, v), v contiguous)
//   q: (3, 124, 124, 25, 5, 5) fp32
//   out: (1, 3, 124, 124, 25) fp32
// out[c,i,j,n] = sum_u log( prod_v (1.1 + atan(10*(x[c,i+u,j+v]*w[c,i,j,n,u,v]
//                                                 - q[c,i,j,n,u,v]))/pi) )

#define IMG   128
#define OUT   124
#define NUM   25
#define SIDE  5
#define NOUT  (3 * OUT * OUT * NUM)            // 1,153,200 outputs
#define WTOT  ((long long)NOUT * NUM)          // 28,830,000 floats in w (and q)
#define OPB   256                              // outputs per block (= block size)
#define FPB   (OPB * NUM)                      // 6400 floats of w (and q) per block
#define FPB4  (FPB / 4)                        // 1600 float4 per block

// Minimax atan, |err| ~ 2e-6 over all inputs. Range-reduce with v_rcp_f32.
__device__ __forceinline__ float fast_atan(float z) {
    float az  = __builtin_fabsf(z);
    float r   = __builtin_amdgcn_rcpf(az);      // ~1 ulp approx reciprocal
    bool  big = az > 1.0f;
    float t   = big ? r : az;                   // t in [0, 1]
    float s   = t * t;
    float p   =                     -0.01172120f;
    p = __builtin_fmaf(p, s,         0.05265332f);
    p = __builtin_fmaf(p, s,        -0.11643287f);
    p = __builtin_fmaf(p, s,         0.19354346f);
    p = __builtin_fmaf(p, s,        -0.33262347f);
    p = __builtin_fmaf(p, s,         0.99997726f);
    float a = t * p;
    a = big ? (1.57079632679489662f - a) : a;
    return __builtin_copysignf(a, z);
}

__global__ __launch_bounds__(OPB) void dendrite_kernel(
    const float* __restrict__ x,
    const float* __restrict__ w,
    const float* __restrict__ q,
    float* __restrict__ out)
{
    __shared__ float lw[FPB];
    __shared__ float lq[FPB];

    const int t   = threadIdx.x;
    const int blk = blockIdx.x;
    const long long base = (long long)blk * FPB;   // float index into w/q

    // ---- Cooperative, fully-coalesced float4 staging of this block's w/q ----
    // base*4 bytes = blk*25600 B -> 16B aligned. WTOT % 4 == 0, so the tail is
    // an exact number of float4s.
    const float4* w4 = (const float4*)(w + base);
    const float4* q4 = (const float4*)(q + base);
    float4* lw4 = (float4*)lw;
    float4* lq4 = (float4*)lq;
    const int nf4 = (int)(((WTOT - base) < (long long)FPB ? (WTOT - base) : (long long)FPB) >> 2);
    #pragma unroll
    for (int idx = t; idx < FPB4; idx += OPB) {
        if (idx < nf4) {
            lw4[idx] = w4[idx];
            lq4[idx] = q4[idx];
        }
    }
    __syncthreads();

    // ---- One output per thread ----
    const int o = blk * OPB + t;
    if (o < NOUT) {
        int rem = o / NUM;                 // (c*OUT + i)*OUT + j
        const int j = rem % OUT;  rem /= OUT;
        const int i = rem % OUT;
        const int c = rem / OUT;

        const float* xp = x + ((long long)c * IMG + i) * IMG + j;  // patch base
        const float* wp = lw + t * NUM;    // LDS stride 25 (odd): 2 lanes/bank, free
        const float* qp = lq + t * NUM;

        float acc = 0.0f;
        #pragma unroll
        for (int u = 0; u < SIDE; ++u) {
            float prod = 1.0f;
            #pragma unroll
            for (int v = 0; v < SIDE; ++v) {
                const float pv = xp[u * IMG + v];            // broadcast-heavy load
                const int   k  = u * SIDE + v;
                const float z  = 10.0f * __builtin_fmaf(pv, wp[k], -qp[k]);
                const float a  = fast_atan(z);
                // (pi + 2a)/(2pi) + 0.6 = 1.1 + a/pi
                prod *= __builtin_fmaf(a, 0.31830988618379067f, 1.1f);
            }
            acc += __logf(prod);           // prod in (0.6^5, 1.6^5): safe
        }
        out[o] = acc;
    }
}

extern "C" void kernel_launch(void* const* d_in, const int* in_sizes, int n_in,
                              void* d_out, int out_size, void* d_ws, size_t ws_size,
                              hipStream_t stream) {
    const float* x = (const float*)d_in[0];
    const float* w = (const float*)d_in[1];
    const float* q = (const float*)d_in[2];
    float* out = (float*)d_out;

    const int grid = (NOUT + OPB - 1) / OPB;   // 4505 blocks
    dendrite_kernel<<<grid, OPB, 0, stream>>>(x, w, q, out);
}